// Round 4
// baseline (255.655 us; speedup 1.0000x reference)
//
#include <hip/hip_runtime.h>

#define B 16384
#define D 1024
#define CL_ALPHA 0.5f
#define MAXM 16   // max samples per class; P(Poisson(1) > 16) ~ 1e-14 per class
#define INV_BD (1.0f / ((float)B * (float)D))

// ---------------------------------------------------------------------------
// K1: bincount + member lists (64 blocks, global atomics). Thread 0 zeroes out.
// ---------------------------------------------------------------------------
__global__ __launch_bounds__(256) void build_kernel(const int* __restrict__ y_true,
                                                    int* __restrict__ counts,
                                                    int* __restrict__ list,
                                                    float* __restrict__ out)
{
    const int i = blockIdx.x * 256 + threadIdx.x;
    if (i == 0) out[0] = 0.0f;
    const int j = y_true[i];
    const int slot = atomicAdd(&counts[j], 1);
    if (slot < MAXM) list[j * MAXM + slot] = i;
}

// ---------------------------------------------------------------------------
// K2: ORDER-PRESERVING 32B descriptor per class (indexed by j — round-3 lesson:
// compaction's random order wrecked HBM locality; keep blockIdx == j).
//   desc[2j]   = { m, kk, inv_bits, i0 }
//   desc[2j+1] = { i1, i2, i3, 0 }
// Moves the dependent chain (y_true[j] -> counts[kk] -> inv, + list load) out
// of the hot kernel: class block then needs exactly 2 memory trips.
// ---------------------------------------------------------------------------
__global__ __launch_bounds__(256) void desc_kernel(const int* __restrict__ y_true,
                                                   const int* __restrict__ counts,
                                                   const int* __restrict__ list,
                                                   int4* __restrict__ desc)
{
    const int j  = blockIdx.x * 256 + threadIdx.x;
    const int m  = counts[j];
    const int kk = y_true[j];
    const int ckk = counts[kk];                          // L2-hot gather
    const float inv = CL_ALPHA / ((float)ckk + 1.0f);    // same formula/rounding as verified
    const int4 mem = ((const int4*)list)[j * (MAXM / 4)]; // slots 0..3 (unused if m==0)
    desc[2 * j]     = make_int4(m, kk, __float_as_int(inv), mem.x);
    desc[2 * j + 1] = make_int4(mem.y, mem.z, mem.w, 0);
}

// ---------------------------------------------------------------------------
// K3: one block per class, blockIdx.x == j (sequential row sweep), 256 threads,
// thread t owns float4 chunk t of each 4KB row.
// Trip 1: desc (32B). Trip 2: ALL 7 rows issued together, branch-free:
// missing members alias member 0 (same address -> L1 hit, no extra HBM) and
// are accumulated with weight 0.0 (bit-exact: acc + 0*x == acc, acc + 1*x ==
// acc + x under fma). __launch_bounds__(256,6) -> ~85 VGPR budget so the
// 7-float4 payload actually stays in flight (round-3 lesson: VGPR=36 meant
// the compiler serialized the loads).
// ---------------------------------------------------------------------------
__global__ __launch_bounds__(256, 6) void class_kernel(const float* __restrict__ y_pred,
                                                       const float* __restrict__ centers,
                                                       const int* __restrict__ list,
                                                       const int4* __restrict__ desc,
                                                       float* __restrict__ out)
{
    const int t = threadIdx.x;
    const int j = blockIdx.x;

    const int4 d0 = desc[2 * j];        // issued together (independent)
    const int4 d1 = desc[2 * j + 1];

    const int m = d0.x;
    if (m == 0) return;                  // uniform; ~37.9% of blocks

    const int   kk  = d0.y;
    const float inv = __int_as_float(d0.z);
    const int   mm  = (m < MAXM) ? m : MAXM;

    const int i0 = d0.w;
    const int i1 = (mm > 1) ? d1.x : i0;  // alias to member 0 -> L1 hit
    const int i2 = (mm > 2) ? d1.y : i0;
    const int i3 = (mm > 3) ? d1.z : i0;

    // ---- trip 2: seven independent float4 loads, all in flight ----
    const float4 cj = ((const float4*)(centers + (size_t)j  * D))[t];
    const float4 yj = ((const float4*)(y_pred  + (size_t)j  * D))[t];
    const float4 ck = ((const float4*)(centers + (size_t)kk * D))[t];
    const float4 a0 = ((const float4*)(y_pred  + (size_t)i0 * D))[t];
    const float4 a1 = ((const float4*)(y_pred  + (size_t)i1 * D))[t];
    const float4 a2 = ((const float4*)(y_pred  + (size_t)i2 * D))[t];
    const float4 a3 = ((const float4*)(y_pred  + (size_t)i3 * D))[t];

    float4 corr;
    corr.x = inv * (ck.x - yj.x) - cj.x;
    corr.y = inv * (ck.y - yj.y) - cj.y;
    corr.z = inv * (ck.z - yj.z) - cj.z;
    corr.w = inv * (ck.w - yj.w) - cj.w;

    const float w1 = (mm > 1) ? 1.0f : 0.0f;
    const float w2 = (mm > 2) ? 1.0f : 0.0f;
    const float w3 = (mm > 3) ? 1.0f : 0.0f;

    float dx, dy, dz, dw, s;
    dx = a0.x + corr.x; dy = a0.y + corr.y; dz = a0.z + corr.z; dw = a0.w + corr.w;
    float acc = dx * dx + dy * dy + dz * dz + dw * dw;

    dx = a1.x + corr.x; dy = a1.y + corr.y; dz = a1.z + corr.z; dw = a1.w + corr.w;
    s = dx * dx + dy * dy + dz * dz + dw * dw;
    acc += w1 * s;

    dx = a2.x + corr.x; dy = a2.y + corr.y; dz = a2.z + corr.z; dw = a2.w + corr.w;
    s = dx * dx + dy * dy + dz * dz + dw * dw;
    acc += w2 * s;

    dx = a3.x + corr.x; dy = a3.y + corr.y; dz = a3.z + corr.z; dw = a3.w + corr.w;
    s = dx * dx + dy * dy + dz * dz + dw * dw;
    acc += w3 * s;

    for (int q = 4; q < mm; ++q) {       // P(m>4) ~ 0.4% of classes
        const float4 a = ((const float4*)(y_pred + (size_t)list[j * MAXM + q] * D))[t];
        dx = a.x + corr.x; dy = a.y + corr.y; dz = a.z + corr.z; dw = a.w + corr.w;
        acc += dx * dx + dy * dy + dz * dz + dw * dw;
    }

    // ---- block reduce -> one atomicAdd (finalize kernel eliminated) ----
#pragma unroll
    for (int off = 32; off > 0; off >>= 1)
        acc += __shfl_down(acc, off, 64);

    __shared__ float smem[4];
    const int lane = t & 63;
    const int wid  = t >> 6;
    if (lane == 0) smem[wid] = acc;
    __syncthreads();
    if (t == 0) {
        const float tot = smem[0] + smem[1] + smem[2] + smem[3];
        atomicAdd(out, tot * INV_BD);
    }
}

extern "C" void kernel_launch(void* const* d_in, const int* in_sizes, int n_in,
                              void* d_out, int out_size, void* d_ws, size_t ws_size,
                              hipStream_t stream)
{
    const int*   y_true  = (const int*)d_in[0];
    const float* y_pred  = (const float*)d_in[1];
    const float* centers = (const float*)d_in[2];
    float* out = (float*)d_out;

    // Workspace: counts 64KB | list 1MB | desc 512KB  (~1.6MB)
    int*  counts = (int*)d_ws;
    int*  list   = counts + B;
    int4* desc   = (int4*)(list + B * MAXM);

    hipMemsetAsync(counts, 0, B * sizeof(int), stream);

    build_kernel<<<B / 256, 256, 0, stream>>>(y_true, counts, list, out);
    desc_kernel <<<B / 256, 256, 0, stream>>>(y_true, counts, list, desc);
    class_kernel<<<B,       256, 0, stream>>>(y_pred, centers, list, desc, out);
}